// Round 7
// baseline (78.142 us; speedup 1.0000x reference)
//
#include <hip/hip_runtime.h>

#define R_ 4
#define S_ 8
#define N_ 4096
#define D_ 64
#define KS_ 128          // K per stage
#define NST_ (N_ / KS_)  // 32 stages

typedef __attribute__((ext_vector_type(8))) short bf16x8;
typedef __attribute__((ext_vector_type(4))) float f32x4;

// global->LDS DMA, 16B per lane; LDS dest is wave-uniform base + lane*16
#define GLOAD_LDS(g, l) __builtin_amdgcn_global_load_lds(                 \
    (const __attribute__((address_space(1))) void*)(g),                   \
    (__attribute__((address_space(3))) void*)(l), 16, 0, 0)

__device__ __forceinline__ unsigned short f2bf(float f) {
    unsigned int u = __float_as_uint(f);
    u = (u + 0x7FFFu + ((u >> 16) & 1u)) >> 16;   // RNE to bf16
    return (unsigned short)u;
}

__device__ __forceinline__ bf16x8 packbf(float4 u, float4 v) {
    bf16x8 f;
    f[0] = (short)f2bf(u.x); f[1] = (short)f2bf(u.y);
    f[2] = (short)f2bf(u.z); f[3] = (short)f2bf(u.w);
    f[4] = (short)f2bf(v.x); f[5] = (short)f2bf(v.y);
    f[6] = (short)f2bf(v.z); f[7] = (short)f2bf(v.w);
    return f;
}

// Kernel 1: ycombT[r][o][k] = bf16( coef[r] * sum_d x[r][k][d] * fc_w[r][o][d] )
__global__ __launch_bounds__(256) void prep_kernel(
    const float* __restrict__ theta, const float* __restrict__ tt,
    const float* __restrict__ x, const float* __restrict__ fc_w,
    unsigned short* __restrict__ ycombT) {
    int r  = blockIdx.x >> 6;
    int kb = blockIdx.x & 63;
    int tid = threadIdx.x;

    __shared__ float xs[64][64];
    __shared__ float ws[64][65];

    const float* xp = x    + ((size_t)r * N_ + (size_t)kb * 64) * D_;
    const float* wp = fc_w + (size_t)r * D_ * D_;
    for (int i = 0; i < 16; ++i) {
        int flat = i * 256 + tid;
        xs[flat >> 6][flat & 63] = xp[flat];
        ws[flat >> 6][flat & 63] = wp[flat];
    }
    float coef = 0.f;
#pragma unroll
    for (int s = 0; s < S_; ++s) coef += theta[r * S_ + s] * tt[r * S_ + s];
    __syncthreads();

    int o = tid & 63, kg = tid >> 6;
    for (int kl = kg; kl < 64; kl += 4) {
        float dot = 0.f;
#pragma unroll
        for (int d = 0; d < D_; ++d) dot += xs[kl][d] * ws[o][d];
        ycombT[(size_t)(r * D_ + o) * N_ + (size_t)kb * 64 + kl] = f2bf(coef * dot);
    }
}

// Kernel 2: block = (r, 64-row tile), full K, 8 waves (wm 16-row group x wk
// 64-k half). B staged via global_load_lds DMA (bypasses VGPR return path),
// source-side XOR swizzle, linear LDS dest, double-buffered, 1 barrier/stage.
// A: register float4 + cvt, 2-stage prefetch. Cross-wk LDS reduction.
__global__ __launch_bounds__(512) void gemm_kernel(
    const float* __restrict__ a, const unsigned short* __restrict__ ycombT,
    const float* __restrict__ fc_b, const float* __restrict__ alpha0p,
    float* __restrict__ out) {
    int bid = blockIdx.x;             // 256 blocks
    int r   = bid & 3;
    int rb  = bid >> 2;               // 64-row tile index
    int tid  = threadIdx.x;
    int wave = tid >> 6;
    int wm   = wave & 3;              // 16-row group
    int wk   = wave >> 2;             // 64-k half per stage
    int lane = tid & 63;
    int l15  = lane & 15;
    int kg   = lane >> 4;

    __shared__ __align__(16) unsigned short bs[2][64][KS_];  // 2 x 16 KB
    __shared__ float red[4][16][65];

    // --- B DMA mapping: wave stages LDS chunks (wave*2, wave*2+1), 1KB each.
    // LDS is linear; swizzle applied on the SOURCE address (rule 21 / m173):
    // lane i of chunk j -> row = 4j + (i>>4), slot = i&15, granule = slot ^ ((row&7)<<1)
    int slot = lane & 15;
    int row0 = wave * 8 + (lane >> 4);
    int row1 = row0 + 4;
    int g0 = slot ^ ((row0 & 7) << 1);
    int g1 = slot ^ ((row1 & 7) << 1);
    const unsigned short* bsrc0 = ycombT + (size_t)(r * D_ + row0) * N_ + g0 * 8;
    const unsigned short* bsrc1 = ycombT + (size_t)(r * D_ + row1) * N_ + g1 * 8;
    char* ldst0 = (char*)bs + wave * 2048;   // + buf*16384
    char* ldst1 = ldst0 + 1024;

    const float* arow = a + ((size_t)(r * N_ + rb * 64 + wm * 16 + l15)) * N_
                          + wk * 64 + kg * 8;

    f32x4 acc0 = {0.f, 0.f, 0.f, 0.f};
    f32x4 acc1 = {0.f, 0.f, 0.f, 0.f};
    f32x4 acc2 = {0.f, 0.f, 0.f, 0.f};
    f32x4 acc3 = {0.f, 0.f, 0.f, 0.f};

    // read-side swizzled slots (ushort offsets): granule ^ ((o-row&7)<<1)
    int swzr = (l15 & 7) << 1;
    int sl0 = ((wk * 8 + 0 + kg) ^ swzr) * 8;
    int sl1 = ((wk * 8 + 4 + kg) ^ swzr) * 8;

    // prologue: DMA stage 0, A-regs for stages 0 and 1
    GLOAD_LDS(bsrc0, ldst0);
    GLOAD_LDS(bsrc1, ldst1);
    float4 ac0 = *(const float4*)(arow + 0);
    float4 ac1 = *(const float4*)(arow + 4);
    float4 ac2 = *(const float4*)(arow + 32);
    float4 ac3 = *(const float4*)(arow + 36);
    float4 an0 = *(const float4*)(arow + KS_ + 0);
    float4 an1 = *(const float4*)(arow + KS_ + 4);
    float4 an2 = *(const float4*)(arow + KS_ + 32);
    float4 an3 = *(const float4*)(arow + KS_ + 36);
    __syncthreads();   // drains DMA (compiler emits vmcnt(0) before s_barrier)

    for (int s = 0; s < NST_; ++s) {
        int buf = s & 1;
        if (s + 1 < NST_) {        // DMA next stage into other buffer
            GLOAD_LDS(bsrc0 + (size_t)(s + 1) * KS_, ldst0 + (buf ^ 1) * 16384);
            GLOAD_LDS(bsrc1 + (size_t)(s + 1) * KS_, ldst1 + (buf ^ 1) * 16384);
        }
        bf16x8 af0 = packbf(ac0, ac1);
        bf16x8 af1 = packbf(ac2, ac3);
        bf16x8 b00 = *(const bf16x8*)&bs[buf][ 0 + l15][sl0];
        bf16x8 b10 = *(const bf16x8*)&bs[buf][16 + l15][sl0];
        bf16x8 b20 = *(const bf16x8*)&bs[buf][32 + l15][sl0];
        bf16x8 b30 = *(const bf16x8*)&bs[buf][48 + l15][sl0];
        acc0 = __builtin_amdgcn_mfma_f32_16x16x32_bf16(af0, b00, acc0, 0, 0, 0);
        acc1 = __builtin_amdgcn_mfma_f32_16x16x32_bf16(af0, b10, acc1, 0, 0, 0);
        acc2 = __builtin_amdgcn_mfma_f32_16x16x32_bf16(af0, b20, acc2, 0, 0, 0);
        acc3 = __builtin_amdgcn_mfma_f32_16x16x32_bf16(af0, b30, acc3, 0, 0, 0);
        bf16x8 b01 = *(const bf16x8*)&bs[buf][ 0 + l15][sl1];
        bf16x8 b11 = *(const bf16x8*)&bs[buf][16 + l15][sl1];
        bf16x8 b21 = *(const bf16x8*)&bs[buf][32 + l15][sl1];
        bf16x8 b31 = *(const bf16x8*)&bs[buf][48 + l15][sl1];
        acc0 = __builtin_amdgcn_mfma_f32_16x16x32_bf16(af1, b01, acc0, 0, 0, 0);
        acc1 = __builtin_amdgcn_mfma_f32_16x16x32_bf16(af1, b11, acc1, 0, 0, 0);
        acc2 = __builtin_amdgcn_mfma_f32_16x16x32_bf16(af1, b21, acc2, 0, 0, 0);
        acc3 = __builtin_amdgcn_mfma_f32_16x16x32_bf16(af1, b31, acc3, 0, 0, 0);

        ac0 = an0; ac1 = an1; ac2 = an2; ac3 = an3;
        if (s + 2 < NST_) {
            an0 = *(const float4*)(arow + (size_t)(s + 2) * KS_ + 0);
            an1 = *(const float4*)(arow + (size_t)(s + 2) * KS_ + 4);
            an2 = *(const float4*)(arow + (size_t)(s + 2) * KS_ + 32);
            an3 = *(const float4*)(arow + (size_t)(s + 2) * KS_ + 36);
        }
        __syncthreads();   // readers of buf done + next-stage DMA drained
    }

    // wk-reduction + epilogue. C/D layout: col=c*16+l15, row_loc=kg*4+j (m89).
    if (wk == 1) {
#pragma unroll
        for (int c = 0; c < 4; ++c) {
            f32x4 acc = (c == 0) ? acc0 : (c == 1) ? acc1 : (c == 2) ? acc2 : acc3;
#pragma unroll
            for (int j = 0; j < 4; ++j)
                red[wm][kg * 4 + j][c * 16 + l15] = acc[j];
        }
    }
    __syncthreads();
    if (wk == 0) {
        const float alpha0 = *alpha0p;
        const size_t diff_off = (size_t)R_ * N_ * D_;   // out = [latent | diffusions]
#pragma unroll
        for (int c = 0; c < 4; ++c) {
            f32x4 acc = (c == 0) ? acc0 : (c == 1) ? acc1 : (c == 2) ? acc2 : acc3;
            int col = c * 16 + l15;
            float b = fc_b[r * D_ + col];
#pragma unroll
            for (int j = 0; j < 4; ++j) {
                int rloc = kg * 4 + j;
                float v = acc[j] + red[wm][rloc][col] + b;
                v = (v >= 0.f) ? v : alpha0 * v;
                out[diff_off + ((size_t)(r * N_ + rb * 64 + wm * 16 + rloc)) * D_ + col] = v;
            }
        }
    }
}

// Kernel 3: 1x1 conv over relation channels + PReLU.
__global__ __launch_bounds__(256) void conv_kernel(
    const float* __restrict__ conv_w, const float* __restrict__ conv_b,
    const float* __restrict__ alpha1p, float* __restrict__ out) {
    const size_t nd = (size_t)N_ * D_;
    const size_t diff_off = (size_t)R_ * nd;
    size_t i = ((size_t)blockIdx.x * 256 + threadIdx.x) * 4;

    float4 d0 = *(const float4*)(out + diff_off + 0 * nd + i);
    float4 d1 = *(const float4*)(out + diff_off + 1 * nd + i);
    float4 d2 = *(const float4*)(out + diff_off + 2 * nd + i);
    float4 d3 = *(const float4*)(out + diff_off + 3 * nd + i);
    const float alpha1 = *alpha1p;
#pragma unroll
    for (int s = 0; s < R_; ++s) {
        float w0 = conv_w[s * R_ + 0], w1 = conv_w[s * R_ + 1];
        float w2 = conv_w[s * R_ + 2], w3 = conv_w[s * R_ + 3];
        float cb = conv_b[s];
        float4 v;
        v.x = cb + w0 * d0.x + w1 * d1.x + w2 * d2.x + w3 * d3.x;
        v.y = cb + w0 * d0.y + w1 * d1.y + w2 * d2.y + w3 * d3.y;
        v.z = cb + w0 * d0.z + w1 * d1.z + w2 * d2.z + w3 * d3.z;
        v.w = cb + w0 * d0.w + w1 * d1.w + w2 * d2.w + w3 * d3.w;
        v.x = (v.x >= 0.f) ? v.x : alpha1 * v.x;
        v.y = (v.y >= 0.f) ? v.y : alpha1 * v.y;
        v.z = (v.z >= 0.f) ? v.z : alpha1 * v.z;
        v.w = (v.w >= 0.f) ? v.w : alpha1 * v.w;
        *(float4*)(out + s * nd + i) = v;
    }
}

extern "C" void kernel_launch(void* const* d_in, const int* in_sizes, int n_in,
                              void* d_out, int out_size, void* d_ws, size_t ws_size,
                              hipStream_t stream) {
    const float* theta  = (const float*)d_in[0];
    const float* tt     = (const float*)d_in[1];
    const float* a      = (const float*)d_in[2];
    const float* x      = (const float*)d_in[3];
    const float* fc_w   = (const float*)d_in[4];
    const float* fc_b   = (const float*)d_in[5];
    const float* conv_w = (const float*)d_in[6];
    const float* conv_b = (const float*)d_in[7];
    const float* alpha0 = (const float*)d_in[8];
    const float* alpha1 = (const float*)d_in[9];
    float* out = (float*)d_out;
    unsigned short* ycombT = (unsigned short*)d_ws;   // 2 MiB bf16

    prep_kernel<<<dim3(R_ * (N_ / 64)), dim3(256), 0, stream>>>(theta, tt, x, fc_w, ycombT);
    gemm_kernel<<<dim3((N_ / 64) * R_), dim3(512), 0, stream>>>(a, ycombT, fc_b, alpha0, out);
    conv_kernel<<<dim3((N_ * D_) / 4 / 256), dim3(256), 0, stream>>>(conv_w, conv_b, alpha1, out);
}

// Round 8
// 71.590 us; speedup vs baseline: 1.0915x; 1.0915x over previous
//
#include <hip/hip_runtime.h>

#define R_ 4
#define S_ 8
#define N_ 4096
#define D_ 64
#define KS_ 128              // K per stage
#define KQ_ 1024             // K per block (quarter)
#define NST_ (KQ_ / KS_)     // 8 stages
#define PART_ELEMS ((size_t)4 * R_ * N_ * D_)   // 16 MB fp32 partials

typedef __attribute__((ext_vector_type(8))) short bf16x8;
typedef __attribute__((ext_vector_type(4))) float f32x4;

__device__ __forceinline__ unsigned short f2bf(float f) {
    unsigned int u = __float_as_uint(f);
    u = (u + 0x7FFFu + ((u >> 16) & 1u)) >> 16;   // RNE to bf16
    return (unsigned short)u;
}

__device__ __forceinline__ bf16x8 packbf(float4 u, float4 v) {
    bf16x8 f;
    f[0] = (short)f2bf(u.x); f[1] = (short)f2bf(u.y);
    f[2] = (short)f2bf(u.z); f[3] = (short)f2bf(u.w);
    f[4] = (short)f2bf(v.x); f[5] = (short)f2bf(v.y);
    f[6] = (short)f2bf(v.z); f[7] = (short)f2bf(v.w);
    return f;
}

// Kernel 1: ycombT[r][o][k] = bf16( coef[r] * sum_d x[r][k][d] * fc_w[r][o][d] )
__global__ __launch_bounds__(256) void prep_kernel(
    const float* __restrict__ theta, const float* __restrict__ tt,
    const float* __restrict__ x, const float* __restrict__ fc_w,
    unsigned short* __restrict__ ycombT) {
    int r  = blockIdx.x >> 6;
    int kb = blockIdx.x & 63;
    int tid = threadIdx.x;

    __shared__ float xs[64][64];
    __shared__ float ws[64][65];

    const float* xp = x    + ((size_t)r * N_ + (size_t)kb * 64) * D_;
    const float* wp = fc_w + (size_t)r * D_ * D_;
    for (int i = 0; i < 16; ++i) {
        int flat = i * 256 + tid;
        xs[flat >> 6][flat & 63] = xp[flat];
        ws[flat >> 6][flat & 63] = wp[flat];
    }
    float coef = 0.f;
#pragma unroll
    for (int s = 0; s < S_; ++s) coef += theta[r * S_ + s] * tt[r * S_ + s];
    __syncthreads();

    int o = tid & 63, kg = tid >> 6;
    for (int kl = kg; kl < 64; kl += 4) {
        float dot = 0.f;
#pragma unroll
        for (int d = 0; d < D_; ++d) dot += xs[kl][d] * ws[o][d];
        ycombT[(size_t)(r * D_ + o) * N_ + (size_t)kb * 64 + kl] = f2bf(coef * dot);
    }
}

// Kernel 2: block = (r, q K-quarter, 256-row group). 8 waves x 32 rows.
// B staged in LDS per stage (16KB, shared by all 8 waves -> 33 MB total B
// traffic), XOR-swizzled, double-buffered, reg-staged (R6-proven).
// Writes raw fp32 partials to ws: part[q][r][n][d].
__global__ __launch_bounds__(512, 2) void gemm_kernel(
    const float* __restrict__ a, const unsigned short* __restrict__ ycombT,
    float* __restrict__ part) {
    int bid = blockIdx.x;             // 256 blocks
    int r   = bid & 3;
    int q   = (bid >> 2) & 3;         // K-quarter; (q,r) -> fixed XCD (bid%16 pattern)
    int rg  = bid >> 4;               // 16 groups of 256 rows
    int tid  = threadIdx.x;
    int wave = tid >> 6;              // 8 waves, 32 rows each
    int lane = tid & 63;
    int l15  = lane & 15;
    int kg   = lane >> 4;

    __shared__ __align__(16) unsigned short bs[2][64][KS_];  // 2 x 16 KB

    // B staging (R6 mapping): thread -> o-row tid>>3, granules g2,g2+1 (16B)
    int srow = tid >> 3, g2 = (tid & 7) * 2;
    int swz  = (srow & 7) << 1;                    // write-side XOR
    const unsigned short* ysrc =
        ycombT + (size_t)(r * D_ + srow) * N_ + (size_t)q * KQ_ + g2 * 8;

    const float* ar0 = a + ((size_t)(r * N_ + rg * 256 + wave * 32 + l15)) * N_
                         + (size_t)q * KQ_ + kg * 8;
    const float* ar1 = ar0 + (size_t)16 * N_;

    f32x4 acc[2][4];
#pragma unroll
    for (int st = 0; st < 2; ++st)
#pragma unroll
        for (int o = 0; o < 4; ++o) acc[st][o] = (f32x4){0.f, 0.f, 0.f, 0.f};

    int swzr = (l15 & 7) << 1;

    float4 an[2][8];                  // raw A, next stage
    bf16x8 af[2][4];                  // bf16 A frags, current stage
    uint4 bv0, bv1;

    // prologue: A stage0 raw -> cvt -> af; A stage1 raw -> an; B stage0 -> LDS; B stage1 -> bv
#pragma unroll
    for (int c = 0; c < 4; ++c) {
        an[0][2 * c]     = *(const float4*)(ar0 + c * 32);
        an[0][2 * c + 1] = *(const float4*)(ar0 + c * 32 + 4);
        an[1][2 * c]     = *(const float4*)(ar1 + c * 32);
        an[1][2 * c + 1] = *(const float4*)(ar1 + c * 32 + 4);
    }
    bv0 = *(const uint4*)(ysrc);
    bv1 = *(const uint4*)(ysrc + 8);
    *(uint4*)&bs[0][srow][((g2    ) ^ swz) * 8] = bv0;
    *(uint4*)&bs[0][srow][((g2 + 1) ^ swz) * 8] = bv1;
#pragma unroll
    for (int st = 0; st < 2; ++st)
#pragma unroll
        for (int c = 0; c < 4; ++c)
            af[st][c] = packbf(an[st][2 * c], an[st][2 * c + 1]);
#pragma unroll
    for (int c = 0; c < 4; ++c) {
        an[0][2 * c]     = *(const float4*)(ar0 + KS_ + c * 32);
        an[0][2 * c + 1] = *(const float4*)(ar0 + KS_ + c * 32 + 4);
        an[1][2 * c]     = *(const float4*)(ar1 + KS_ + c * 32);
        an[1][2 * c + 1] = *(const float4*)(ar1 + KS_ + c * 32 + 4);
    }
    bv0 = *(const uint4*)(ysrc + KS_);
    bv1 = *(const uint4*)(ysrc + KS_ + 8);
    __syncthreads();

    for (int s = 0; s < NST_; ++s) {
        int buf = s & 1;
        // compute stage s: B frag (o,c) reused across both row-sets
#pragma unroll
        for (int c = 0; c < 4; ++c) {
            int sl = ((c * 4 + kg) ^ swzr) * 8;
            bf16x8 b0 = *(const bf16x8*)&bs[buf][ 0 + l15][sl];
            bf16x8 b1 = *(const bf16x8*)&bs[buf][16 + l15][sl];
            bf16x8 b2 = *(const bf16x8*)&bs[buf][32 + l15][sl];
            bf16x8 b3 = *(const bf16x8*)&bs[buf][48 + l15][sl];
            acc[0][0] = __builtin_amdgcn_mfma_f32_16x16x32_bf16(af[0][c], b0, acc[0][0], 0, 0, 0);
            acc[0][1] = __builtin_amdgcn_mfma_f32_16x16x32_bf16(af[0][c], b1, acc[0][1], 0, 0, 0);
            acc[0][2] = __builtin_amdgcn_mfma_f32_16x16x32_bf16(af[0][c], b2, acc[0][2], 0, 0, 0);
            acc[0][3] = __builtin_amdgcn_mfma_f32_16x16x32_bf16(af[0][c], b3, acc[0][3], 0, 0, 0);
            acc[1][0] = __builtin_amdgcn_mfma_f32_16x16x32_bf16(af[1][c], b0, acc[1][0], 0, 0, 0);
            acc[1][1] = __builtin_amdgcn_mfma_f32_16x16x32_bf16(af[1][c], b1, acc[1][1], 0, 0, 0);
            acc[1][2] = __builtin_amdgcn_mfma_f32_16x16x32_bf16(af[1][c], b2, acc[1][2], 0, 0, 0);
            acc[1][3] = __builtin_amdgcn_mfma_f32_16x16x32_bf16(af[1][c], b3, acc[1][3], 0, 0, 0);
        }
        // A: cvt (s+1) raw -> frags; issue raw loads for s+2
#pragma unroll
        for (int st = 0; st < 2; ++st)
#pragma unroll
            for (int c = 0; c < 4; ++c)
                af[st][c] = packbf(an[st][2 * c], an[st][2 * c + 1]);
        if (s + 2 < NST_) {
            size_t ko = (size_t)(s + 2) * KS_;
#pragma unroll
            for (int c = 0; c < 4; ++c) {
                an[0][2 * c]     = *(const float4*)(ar0 + ko + c * 32);
                an[0][2 * c + 1] = *(const float4*)(ar0 + ko + c * 32 + 4);
                an[1][2 * c]     = *(const float4*)(ar1 + ko + c * 32);
                an[1][2 * c + 1] = *(const float4*)(ar1 + ko + c * 32 + 4);
            }
        }
        __syncthreads();
        if (s + 1 < NST_) {
            *(uint4*)&bs[buf ^ 1][srow][((g2    ) ^ swz) * 8] = bv0;
            *(uint4*)&bs[buf ^ 1][srow][((g2 + 1) ^ swz) * 8] = bv1;
            if (s + 2 < NST_) {
                bv0 = *(const uint4*)(ysrc + (size_t)(s + 2) * KS_);
                bv1 = *(const uint4*)(ysrc + (size_t)(s + 2) * KS_ + 8);
            }
            __syncthreads();
        }
    }

    // partial write: part[q][r][row][col]. C/D layout: col=c*16+l15, rloc=kg*4+j (m89).
    float* pb = part + (((size_t)(q * R_ + r) * N_) + rg * 256 + wave * 32) * D_;
#pragma unroll
    for (int st = 0; st < 2; ++st)
#pragma unroll
        for (int c = 0; c < 4; ++c)
#pragma unroll
            for (int j = 0; j < 4; ++j)
                pb[(size_t)(st * 16 + kg * 4 + j) * D_ + c * 16 + l15] = acc[st][c][j];
}

// Kernel 3: combine partials -> bias+PReLU (diffusions) -> 1x1 conv+PReLU (latent)
__global__ __launch_bounds__(256) void combine_kernel(
    const float* __restrict__ part, const float* __restrict__ fc_b,
    const float* __restrict__ conv_w, const float* __restrict__ conv_b,
    const float* __restrict__ alpha0p, const float* __restrict__ alpha1p,
    float* __restrict__ out) {
    const size_t nd = (size_t)N_ * D_;
    const size_t diff_off = (size_t)R_ * nd;
    size_t i = ((size_t)blockIdx.x * 256 + threadIdx.x) * 4;
    int col0 = (int)(i & 63);
    const float alpha0 = *alpha0p, alpha1 = *alpha1p;

    float4 diff[4];
#pragma unroll
    for (int r = 0; r < R_; ++r) {
        float4 s = {0.f, 0.f, 0.f, 0.f};
#pragma unroll
        for (int qq = 0; qq < 4; ++qq) {
            float4 p = *(const float4*)(part + (size_t)(qq * R_ + r) * nd + i);
            s.x += p.x; s.y += p.y; s.z += p.z; s.w += p.w;
        }
        float4 b = *(const float4*)(fc_b + r * D_ + col0);
        s.x += b.x; s.y += b.y; s.z += b.z; s.w += b.w;
        s.x = (s.x >= 0.f) ? s.x : alpha0 * s.x;
        s.y = (s.y >= 0.f) ? s.y : alpha0 * s.y;
        s.z = (s.z >= 0.f) ? s.z : alpha0 * s.z;
        s.w = (s.w >= 0.f) ? s.w : alpha0 * s.w;
        diff[r] = s;
        *(float4*)(out + diff_off + r * nd + i) = s;
    }
#pragma unroll
    for (int sx = 0; sx < R_; ++sx) {
        float w0 = conv_w[sx * R_ + 0], w1 = conv_w[sx * R_ + 1];
        float w2 = conv_w[sx * R_ + 2], w3 = conv_w[sx * R_ + 3];
        float cb = conv_b[sx];
        float4 v;
        v.x = cb + w0 * diff[0].x + w1 * diff[1].x + w2 * diff[2].x + w3 * diff[3].x;
        v.y = cb + w0 * diff[0].y + w1 * diff[1].y + w2 * diff[2].y + w3 * diff[3].y;
        v.z = cb + w0 * diff[0].z + w1 * diff[1].z + w2 * diff[2].z + w3 * diff[3].z;
        v.w = cb + w0 * diff[0].w + w1 * diff[1].w + w2 * diff[2].w + w3 * diff[3].w;
        v.x = (v.x >= 0.f) ? v.x : alpha1 * v.x;
        v.y = (v.y >= 0.f) ? v.y : alpha1 * v.y;
        v.z = (v.z >= 0.f) ? v.z : alpha1 * v.z;
        v.w = (v.w >= 0.f) ? v.w : alpha1 * v.w;
        *(float4*)(out + sx * nd + i) = v;
    }
}

extern "C" void kernel_launch(void* const* d_in, const int* in_sizes, int n_in,
                              void* d_out, int out_size, void* d_ws, size_t ws_size,
                              hipStream_t stream) {
    const float* theta  = (const float*)d_in[0];
    const float* tt     = (const float*)d_in[1];
    const float* a      = (const float*)d_in[2];
    const float* x      = (const float*)d_in[3];
    const float* fc_w   = (const float*)d_in[4];
    const float* fc_b   = (const float*)d_in[5];
    const float* conv_w = (const float*)d_in[6];
    const float* conv_b = (const float*)d_in[7];
    const float* alpha0 = (const float*)d_in[8];
    const float* alpha1 = (const float*)d_in[9];
    float* out = (float*)d_out;

    float* part = (float*)d_ws;                                       // 16 MiB fp32
    unsigned short* ycombT =
        (unsigned short*)((char*)d_ws + PART_ELEMS * sizeof(float));  // 2 MiB bf16

    prep_kernel<<<dim3(R_ * (N_ / 64)), dim3(256), 0, stream>>>(theta, tt, x, fc_w, ycombT);
    gemm_kernel<<<dim3(256), dim3(512), 0, stream>>>(a, ycombT, part);
    combine_kernel<<<dim3((N_ * D_) / 4 / 256), dim3(256), 0, stream>>>(
        part, fc_b, conv_w, conv_b, alpha0, alpha1, out);
}

// Round 9
// 58.814 us; speedup vs baseline: 1.3286x; 1.2172x over previous
//
#include <hip/hip_runtime.h>

#define R_ 4
#define S_ 8
#define N_ 4096
#define D_ 64
#define KS_ 128          // K per stage
#define NST_ (N_ / KS_)  // 32 stages

typedef __attribute__((ext_vector_type(8))) short bf16x8;
typedef __attribute__((ext_vector_type(4))) float f32x4;

__device__ __forceinline__ unsigned int f2bf(float f) {
    unsigned int u = __float_as_uint(f);
    return (u + 0x7FFFu + ((u >> 16) & 1u)) >> 16;   // RNE to bf16
}

// Kernel 1: ycombT[r][o][k] = bf16( coef[r] * sum_d x[r][k][d] * fc_w[r][o][d] )
__global__ __launch_bounds__(256) void prep_kernel(
    const float* __restrict__ theta, const float* __restrict__ tt,
    const float* __restrict__ x, const float* __restrict__ fc_w,
    unsigned short* __restrict__ ycombT) {
    int r  = blockIdx.x >> 6;
    int kb = blockIdx.x & 63;
    int tid = threadIdx.x;

    __shared__ float xs[64][64];
    __shared__ float ws[64][65];

    const float* xp = x    + ((size_t)r * N_ + (size_t)kb * 64) * D_;
    const float* wp = fc_w + (size_t)r * D_ * D_;
    for (int i = 0; i < 16; ++i) {
        int flat = i * 256 + tid;
        xs[flat >> 6][flat & 63] = xp[flat];
        ws[flat >> 6][flat & 63] = wp[flat];
    }
    float coef = 0.f;
#pragma unroll
    for (int s = 0; s < S_; ++s) coef += theta[r * S_ + s] * tt[r * S_ + s];
    __syncthreads();

    int o = tid & 63, kg = tid >> 6;
    for (int kl = kg; kl < 64; kl += 4) {
        float dot = 0.f;
#pragma unroll
        for (int d = 0; d < D_; ++d) dot += xs[kl][d] * ws[o][d];
        ycombT[(size_t)(r * D_ + o) * N_ + (size_t)kb * 64 + kl] =
            (unsigned short)f2bf(coef * dot);
    }
}

// Kernel 2: R6 structure (block = (r, 64 rows), full K, 8 waves wm x wk,
// double-buffered 32-stage pipeline) but A staged through LDS with DENSE
// loads: one inst = 2 rows x 512B contiguous (vs 16 rows x 128B scattered).
// Both A and B tiles [64][128] bf16, XOR-swizzled 16B granules.
__global__ __launch_bounds__(512) void gemm_kernel(
    const float* __restrict__ a, const unsigned short* __restrict__ ycombT,
    const float* __restrict__ fc_b, const float* __restrict__ alpha0p,
    float* __restrict__ out) {
    int bid = blockIdx.x;             // 256 blocks
    int r   = bid & 3;
    int rb  = bid >> 2;               // 64-row tile index
    int tid  = threadIdx.x;
    int wave = tid >> 6;
    int wm   = wave & 3;              // 16-row group
    int wk   = wave >> 2;             // 64-k half per stage
    int lane = tid & 63;
    int l15  = lane & 15;
    int kg   = lane >> 4;

    // pool: [A0:0-16K][A1:16-32K][B0:32-48K][B1:48-64K]; red overlays at end
    __shared__ __align__(16) char pool[65536];
#define ABASE(buf) ((buf) * 16384)
#define BBASE(buf) (32768 + (buf) * 16384)

    // ---- A staging map (dense): thread t covers rows {j*16 + (t>>5)},
    // floats k0=(t&31)*4 .. +3 of the 128-wide stage tile.
    int arow_loc = tid >> 5;               // 0..15
    int ak       = (tid & 31) * 4;         // float offset in stage tile
    int agran    = (tid & 31) >> 1;        // 16B granule
    int ahalf    = tid & 1;                // 8B half of granule
    int swzA     = (arow_loc & 7) << 1;    // rowj&7 == arow_loc&7 (j*16 = 0 mod 8)
    const float* asrc = a + ((size_t)(r * N_ + rb * 64)) * N_;

    // ---- B staging map (R6-proven): thread -> o-row tid>>3, granules g2,g2+1
    int srow = tid >> 3, g2 = (tid & 7) * 2;
    int swzB = (srow & 7) << 1;
    const unsigned short* ysrc = ycombT + (size_t)(r * D_ + srow) * N_ + g2 * 8;

    // ---- frag read slots (both A and B share the k-granule layout)
    int swzr = (l15 & 7) << 1;

    f32x4 acc0 = {0.f, 0.f, 0.f, 0.f};
    f32x4 acc1 = {0.f, 0.f, 0.f, 0.f};
    f32x4 acc2 = {0.f, 0.f, 0.f, 0.f};
    f32x4 acc3 = {0.f, 0.f, 0.f, 0.f};

    float4 an[4];
    uint4  bv0, bv1;

    auto loadA = [&](int s) {
#pragma unroll
        for (int j = 0; j < 4; ++j)
            an[j] = *(const float4*)(asrc + (size_t)(j * 16 + arow_loc) * N_
                                          + (size_t)s * KS_ + ak);
    };
    auto loadB = [&](int s) {
        bv0 = *(const uint4*)(ysrc + (size_t)s * KS_);
        bv1 = *(const uint4*)(ysrc + (size_t)s * KS_ + 8);
    };
    auto writeA = [&](int buf) {
#pragma unroll
        for (int j = 0; j < 4; ++j) {
            int rowj = j * 16 + arow_loc;
            uint2 p;
            p.x = (f2bf(an[j].y) << 16) | f2bf(an[j].x);
            p.y = (f2bf(an[j].w) << 16) | f2bf(an[j].z);
            *(uint2*)(pool + ABASE(buf) + rowj * 256
                      + ((agran ^ swzA) << 4) + (ahalf << 3)) = p;
        }
    };
    auto writeB = [&](int buf) {
        *(uint4*)(pool + BBASE(buf) + srow * 256 + (((g2    ) ^ swzB) << 4)) = bv0;
        *(uint4*)(pool + BBASE(buf) + srow * 256 + (((g2 + 1) ^ swzB) << 4)) = bv1;
    };
    auto compute = [&](int buf) {
#pragma unroll
        for (int step = 0; step < 2; ++step) {
            int slot = (((wk * 8 + step * 4 + kg) ^ swzr)) << 4;
            bf16x8 af = *(const bf16x8*)(pool + ABASE(buf) + (wm * 16 + l15) * 256 + slot);
            bf16x8 b0 = *(const bf16x8*)(pool + BBASE(buf) + ( 0 + l15) * 256 + slot);
            bf16x8 b1 = *(const bf16x8*)(pool + BBASE(buf) + (16 + l15) * 256 + slot);
            bf16x8 b2 = *(const bf16x8*)(pool + BBASE(buf) + (32 + l15) * 256 + slot);
            bf16x8 b3 = *(const bf16x8*)(pool + BBASE(buf) + (48 + l15) * 256 + slot);
            acc0 = __builtin_amdgcn_mfma_f32_16x16x32_bf16(af, b0, acc0, 0, 0, 0);
            acc1 = __builtin_amdgcn_mfma_f32_16x16x32_bf16(af, b1, acc1, 0, 0, 0);
            acc2 = __builtin_amdgcn_mfma_f32_16x16x32_bf16(af, b2, acc2, 0, 0, 0);
            acc3 = __builtin_amdgcn_mfma_f32_16x16x32_bf16(af, b3, acc3, 0, 0, 0);
        }
    };

    // prologue: stage 0 -> LDS buf0; stage 1 raw -> regs
    loadA(0); loadB(0);
    writeA(0); writeB(0);
    loadA(1); loadB(1);
    __syncthreads();

#pragma unroll 2
    for (int s = 0; s < NST_; ++s) {
        int buf = s & 1;
        compute(buf);
        __syncthreads();                       // all reads of buf done
        if (s + 1 < NST_) {
            writeA(buf ^ 1); writeB(buf ^ 1);  // stage s+1 into other buffer
            if (s + 2 < NST_) { loadA(s + 2); loadB(s + 2); }
            __syncthreads();                   // writes visible before next compute
        }
    }

    // wk-reduction + epilogue (red overlays pool; all LDS dead after last barrier)
    float (*red)[16][65] = (float (*)[16][65])pool;
    if (wk == 1) {
#pragma unroll
        for (int c = 0; c < 4; ++c) {
            f32x4 acc = (c == 0) ? acc0 : (c == 1) ? acc1 : (c == 2) ? acc2 : acc3;
#pragma unroll
            for (int j = 0; j < 4; ++j)
                red[wm][kg * 4 + j][c * 16 + l15] = acc[j];
        }
    }
    __syncthreads();
    if (wk == 0) {
        const float alpha0 = *alpha0p;
        const size_t diff_off = (size_t)R_ * N_ * D_;   // out = [latent | diffusions]
#pragma unroll
        for (int c = 0; c < 4; ++c) {
            f32x4 acc = (c == 0) ? acc0 : (c == 1) ? acc1 : (c == 2) ? acc2 : acc3;
            int col = c * 16 + l15;
            float b = fc_b[r * D_ + col];
#pragma unroll
            for (int j = 0; j < 4; ++j) {
                int rloc = kg * 4 + j;
                float v = acc[j] + red[wm][rloc][col] + b;
                v = (v >= 0.f) ? v : alpha0 * v;
                out[diff_off + ((size_t)(r * N_ + rb * 64 + wm * 16 + rloc)) * D_ + col] = v;
            }
        }
    }
}

// Kernel 3: 1x1 conv over relation channels + PReLU.
__global__ __launch_bounds__(256) void conv_kernel(
    const float* __restrict__ conv_w, const float* __restrict__ conv_b,
    const float* __restrict__ alpha1p, float* __restrict__ out) {
    const size_t nd = (size_t)N_ * D_;
    const size_t diff_off = (size_t)R_ * nd;
    size_t i = ((size_t)blockIdx.x * 256 + threadIdx.x) * 4;

    float4 d0 = *(const float4*)(out + diff_off + 0 * nd + i);
    float4 d1 = *(const float4*)(out + diff_off + 1 * nd + i);
    float4 d2 = *(const float4*)(out + diff_off + 2 * nd + i);
    float4 d3 = *(const float4*)(out + diff_off + 3 * nd + i);
    const float alpha1 = *alpha1p;
#pragma unroll
    for (int s = 0; s < R_; ++s) {
        float w0 = conv_w[s * R_ + 0], w1 = conv_w[s * R_ + 1];
        float w2 = conv_w[s * R_ + 2], w3 = conv_w[s * R_ + 3];
        float cb = conv_b[s];
        float4 v;
        v.x = cb + w0 * d0.x + w1 * d1.x + w2 * d2.x + w3 * d3.x;
        v.y = cb + w0 * d0.y + w1 * d1.y + w2 * d2.y + w3 * d3.y;
        v.z = cb + w0 * d0.z + w1 * d1.z + w2 * d2.z + w3 * d3.z;
        v.w = cb + w0 * d0.w + w1 * d1.w + w2 * d2.w + w3 * d3.w;
        v.x = (v.x >= 0.f) ? v.x : alpha1 * v.x;
        v.y = (v.y >= 0.f) ? v.y : alpha1 * v.y;
        v.z = (v.z >= 0.f) ? v.z : alpha1 * v.z;
        v.w = (v.w >= 0.f) ? v.w : alpha1 * v.w;
        *(float4*)(out + s * nd + i) = v;
    }
}

extern "C" void kernel_launch(void* const* d_in, const int* in_sizes, int n_in,
                              void* d_out, int out_size, void* d_ws, size_t ws_size,
                              hipStream_t stream) {
    const float* theta  = (const float*)d_in[0];
    const float* tt     = (const float*)d_in[1];
    const float* a      = (const float*)d_in[2];
    const float* x      = (const float*)d_in[3];
    const float* fc_w   = (const float*)d_in[4];
    const float* fc_b   = (const float*)d_in[5];
    const float* conv_w = (const float*)d_in[6];
    const float* conv_b = (const float*)d_in[7];
    const float* alpha0 = (const float*)d_in[8];
    const float* alpha1 = (const float*)d_in[9];
    float* out = (float*)d_out;
    unsigned short* ycombT = (unsigned short*)d_ws;   // 2 MiB bf16

    prep_kernel<<<dim3(R_ * (N_ / 64)), dim3(256), 0, stream>>>(theta, tt, x, fc_w, ycombT);
    gemm_kernel<<<dim3((N_ / 64) * R_), dim3(512), 0, stream>>>(a, ycombT, fc_b, alpha0, out);
    conv_kernel<<<dim3((N_ * D_) / 4 / 256), dim3(256), 0, stream>>>(conv_w, conv_b, alpha1, out);
}